// Round 1
// baseline (240.316 us; speedup 1.0000x reference)
//
#include <hip/hip_runtime.h>
#include <hip/hip_bf16.h>

#define B_     32
#define N_     16384
#define D_     64
#define C_     36
#define FG_    32
#define ALPHA_ 10.0f

// ---------------------------------------------------------------------------
// Kernel 1: fused normalize + cosine + softmax + accumulation.
// grid = (32 n-blocks, 32 batches), block = 256 threads (4 waves).
// Each block handles 512 rows of one batch, in 8 chunks of 64 rows.
// Accumulates partial weighted_sum (64x36) and self_product (36) via atomics.
// ---------------------------------------------------------------------------
__global__ __launch_bounds__(256) void k_accum(
    const float* __restrict__ x, const float* __restrict__ cent,
    float* __restrict__ wsA, float* __restrict__ spA)
{
  const int t  = threadIdx.x;
  const int b  = blockIdx.y;
  const int nb = blockIdx.x;

  __shared__ __align__(16) float cnl[D_][4][12];   // normalized centroids, c-group padded to 12
  __shared__ __align__(16) float xs[64][65];       // raw x chunk, row-major, pad 65
  __shared__ __align__(16) float asgT[C_][68];     // (assign * rn) transposed, pad 68
  __shared__ float psum[64][5];                    // softmax partial sums, pad 5
  __shared__ float nrmc[C_];

  // centroid column norms (tiny; recomputed per block, L2-cached)
  if (t < C_) {
    float ss = 0.f;
    for (int d = 0; d < D_; ++d) { float v = cent[d*C_ + t]; ss = fmaf(v, v, ss); }
    nrmc[t] = 1.f / fmaxf(sqrtf(ss), 1e-12f);
  }
  __syncthreads();
  for (int idx = t; idx < D_*4*12; idx += 256) {
    int d = idx / 48; int rem = idx - d*48; int cg = rem / 12; int k = rem - cg*12;
    int c = cg*9 + k;
    cnl[d][cg][k] = (k < 9) ? cent[d*C_ + c] * nrmc[c] : 0.f;
  }
  __syncthreads();

  const int r  = t & 63;     // row within chunk (stage B), d (stage C)
  const int cg = t >> 6;     // c-group: 9 clusters each, uniform per wave
  const int c0 = cg * 9;

  float acc[9], sp[9];
  #pragma unroll
  for (int k = 0; k < 9; ++k) { acc[k] = 0.f; sp[k] = 0.f; }

  const size_t rowbase = ((size_t)b * N_ + (size_t)nb * 512);

  for (int ch = 0; ch < 512; ch += 64) {
    // ---- Stage A: coalesced global -> LDS (64 rows x 64 floats) ----
    const float4* xg = reinterpret_cast<const float4*>(x + (rowbase + ch) * D_);
    #pragma unroll
    for (int k = 0; k < 4; ++k) {
      int i4 = k*256 + t;
      float4 v = xg[i4];
      int rr = i4 >> 4;
      int dd = (i4 & 15) << 2;
      xs[rr][dd+0] = v.x; xs[rr][dd+1] = v.y; xs[rr][dd+2] = v.z; xs[rr][dd+3] = v.w;
    }
    __syncthreads();

    // ---- Stage B: per-row dots + softmax; thread = (row r, c-group cg) ----
    float q[9];
    #pragma unroll
    for (int k = 0; k < 9; ++k) q[k] = 0.f;
    float ss = 0.f;
    #pragma unroll 4
    for (int d = 0; d < 64; ++d) {
      float xv = xs[r][d];                     // lanes=r, stride 65: conflict-free
      ss = fmaf(xv, xv, ss);
      const float4* cp = reinterpret_cast<const float4*>(&cnl[d][cg][0]); // wave-uniform broadcast
      float4 ca = cp[0];
      float4 cb = cp[1];
      float  cc = cnl[d][cg][8];
      q[0] = fmaf(xv, ca.x, q[0]);
      q[1] = fmaf(xv, ca.y, q[1]);
      q[2] = fmaf(xv, ca.z, q[2]);
      q[3] = fmaf(xv, ca.w, q[3]);
      q[4] = fmaf(xv, cb.x, q[4]);
      q[5] = fmaf(xv, cb.y, q[5]);
      q[6] = fmaf(xv, cb.z, q[6]);
      q[7] = fmaf(xv, cb.w, q[7]);
      q[8] = fmaf(xv, cc,   q[8]);
    }
    float rn = 1.f / fmaxf(sqrtf(ss), 1e-12f);
    float e[9]; float ps = 0.f;
    #pragma unroll
    for (int k = 0; k < 9; ++k) { e[k] = __expf(ALPHA_ * rn * q[k]); ps += e[k]; }
    psum[r][cg] = ps;
    __syncthreads();
    float denom = psum[r][0] + psum[r][1] + psum[r][2] + psum[r][3];
    float inva = 1.f / denom;                   // softmax w/o max-sub: logits bounded by 10
    float abm  = inva * rn;
    #pragma unroll
    for (int k = 0; k < 9; ++k) {
      sp[k] = fmaf(q[k]*rn, e[k]*inva, sp[k]); // cos * assign
      asgT[c0 + k][r] = e[k] * abm;            // assign * rn; lanes=r stride 1
    }
    __syncthreads();

    // ---- Stage C: rank-1 updates; thread = (d = r, c-group cg) ----
    {
      const int d = r;
      #pragma unroll 2
      for (int r4 = 0; r4 < 64; r4 += 4) {
        float x0 = xs[r4+0][d];                // lanes=d, stride 1
        float x1 = xs[r4+1][d];
        float x2 = xs[r4+2][d];
        float x3 = xs[r4+3][d];
        #pragma unroll
        for (int k = 0; k < 9; ++k) {
          float4 av = *reinterpret_cast<const float4*>(&asgT[c0+k][r4]); // broadcast b128
          acc[k] = fmaf(x0, av.x, acc[k]);
          acc[k] = fmaf(x1, av.y, acc[k]);
          acc[k] = fmaf(x2, av.z, acc[k]);
          acc[k] = fmaf(x3, av.w, acc[k]);
        }
      }
    }
    __syncthreads();
  }

  // ---- epilogue: flush partials ----
  {
    const int d = r;
    #pragma unroll
    for (int k = 0; k < 9; ++k)
      atomicAdd(&wsA[((size_t)b*D_ + d)*C_ + c0 + k], acc[k]);
  }
  #pragma unroll
  for (int k = 0; k < 9; ++k) {
    float v = sp[k];
    for (int off = 32; off; off >>= 1) v += __shfl_down(v, off);
    if (r == 0) atomicAdd(&spA[b*C_ + c0 + k], v);
  }
}

// ---------------------------------------------------------------------------
// Kernel 2: finalize. One block per batch.
// vlad[c][d] = ws[d][c] - cn[d][c]*sp[c]; per-cluster L2 norm; global L2 norm;
// write first 32*64 elements.
// ---------------------------------------------------------------------------
__global__ __launch_bounds__(256) void k_final(
    const float* __restrict__ cent, const float* __restrict__ wsA,
    const float* __restrict__ spA, float* __restrict__ out)
{
  const int b = blockIdx.x;
  const int t = threadIdx.x;
  __shared__ float nrmc[C_];
  __shared__ float vl[C_][65];
  __shared__ float rc[C_];
  __shared__ float red[4];

  if (t < C_) {
    float ss = 0.f;
    for (int d = 0; d < D_; ++d) { float v = cent[d*C_ + t]; ss = fmaf(v, v, ss); }
    nrmc[t] = 1.f / fmaxf(sqrtf(ss), 1e-12f);
  }
  __syncthreads();
  for (int idx = t; idx < D_*C_; idx += 256) {
    int d = idx / C_, c = idx - d*C_;
    float cn = cent[d*C_ + c] * nrmc[c];
    float w  = wsA[((size_t)b*D_ + d)*C_ + c];
    vl[c][d] = w - cn * spA[b*C_ + c];
  }
  __syncthreads();
  if (t < C_) {
    float ss = 0.f;
    for (int d = 0; d < D_; ++d) { float v = vl[t][d]; ss = fmaf(v, v, ss); }
    rc[t] = 1.f / fmaxf(sqrtf(ss), 1e-12f);
  }
  __syncthreads();
  float p = 0.f;
  for (int idx = t; idx < D_*C_; idx += 256) {
    int c = idx >> 6, d = idx & 63;
    float v = vl[c][d] * rc[c];
    p = fmaf(v, v, p);
  }
  for (int off = 32; off; off >>= 1) p += __shfl_down(p, off);
  if ((t & 63) == 0) red[t >> 6] = p;
  __syncthreads();
  float S = red[0] + red[1] + red[2] + red[3];
  float rg = 1.f / fmaxf(sqrtf(S), 1e-12f);
  for (int idx = t; idx < FG_*D_; idx += 256) {
    int c = idx >> 6, d = idx & 63;
    out[(size_t)b*(FG_*D_) + idx] = vl[c][d] * rc[c] * rg;
  }
}

extern "C" void kernel_launch(void* const* d_in, const int* in_sizes, int n_in,
                              void* d_out, int out_size, void* d_ws, size_t ws_size,
                              hipStream_t stream) {
  const float* x    = (const float*)d_in[0];
  const float* cent = (const float*)d_in[1];
  float* out = (float*)d_out;

  float* wsA = (float*)d_ws;               // 32*64*36 = 73728 floats
  float* spA = wsA + (size_t)B_*D_*C_;     // 32*36   = 1152 floats

  hipMemsetAsync(d_ws, 0, ((size_t)B_*D_*C_ + (size_t)B_*C_) * sizeof(float), stream);

  dim3 g1(32, B_);
  k_accum<<<g1, 256, 0, stream>>>(x, cent, wsA, spA);
  k_final<<<B_, 256, 0, stream>>>(cent, wsA, spA, out);
}

// Round 2
// 95.284 us; speedup vs baseline: 2.5221x; 2.5221x over previous
//
#include <hip/hip_runtime.h>
#include <hip/hip_bf16.h>

#define B_     32
#define N_     16384
#define D_     64
#define C_     36
#define CP_    48     // padded cluster count (3 x 16 MFMA tiles)
#define FG_    32
#define ALPHA_ 10.0f

typedef __attribute__((ext_vector_type(8))) short bf16x8;
typedef __attribute__((ext_vector_type(4))) short bf16x4;
typedef __attribute__((ext_vector_type(4))) float f32x4;

#define MFMA(a,b,c) __builtin_amdgcn_mfma_f32_16x16x32_bf16(a,b,c,0,0,0)

__device__ __forceinline__ unsigned short f2bf(float f){
  unsigned u = __float_as_uint(f);
  unsigned r = u + 0x7fffu + ((u >> 16) & 1u);   // RNE; inputs finite
  return (unsigned short)(r >> 16);
}

// convert v -> hi bf16 (slot J of H) and residual lo bf16 (slot J of L)
#define CVT1(v, H, L, J) { unsigned short hb_ = f2bf(v); (H)[J] = (short)hb_; \
  (L)[J] = (short)f2bf((v) - __uint_as_float((unsigned)hb_ << 16)); }

__device__ __forceinline__ bf16x8 ld_frag(const unsigned short* p){
  bf16x4 a = *(const bf16x4*)p;
  bf16x4 b = *(const bf16x4*)(p + 4);
  return __builtin_shufflevector(a, b, 0,1,2,3,4,5,6,7);
}

// ---------------------------------------------------------------------------
// Fused kernel: per-wave independent pipeline.
// grid = 1024 blocks (32 per batch), block = 256 threads = 4 waves.
// Wave processes 128 rows: 4 units of 32 rows (2 groups of 16).
// Per 16-row group: global load -> row norm -> bf16 hi/lo frags ->
//   cos MFMA (D[c][row]) -> softmax -> asg/xt to LDS.
// Per 32-row unit: ws MFMA  D[c][d] += asg^T(c x row) * x(row x d).
// ---------------------------------------------------------------------------
__global__ __launch_bounds__(256, 3) void k_accum(
    const float* __restrict__ x, const float* __restrict__ cent,
    float* __restrict__ wsA, float* __restrict__ spA)
{
  const int t   = threadIdx.x;
  const int wid = t >> 6;
  const int l   = t & 63;
  const int lm  = l & 15;
  const int lg  = l >> 4;
  const int b   = blockIdx.x >> 5;
  const int nb  = blockIdx.x & 31;

  __shared__ float nrmc[C_];
  __shared__ __align__(16) union {
    struct { unsigned short asg[4][CP_*36]; unsigned short xt[4][64*36]; } m;
    float red[CP_*65];
  } sh;

  if (t < C_) {
    float ss = 0.f;
    for (int d = 0; d < D_; ++d) { float v = cent[d*C_ + t]; ss = fmaf(v, v, ss); }
    nrmc[t] = 1.f / fmaxf(sqrtf(ss), 1e-12f);
  }
  __syncthreads();

  // normalized-centroid A-fragments: A[m=c][k=d], c = 16*ct+lm, d = 32*s+8*lg+j
  bf16x8 cnf[3][2];
  #pragma unroll
  for (int ct = 0; ct < 3; ++ct) {
    #pragma unroll
    for (int s = 0; s < 2; ++s) {
      bf16x8 f;
      #pragma unroll
      for (int j = 0; j < 8; ++j) {
        int d = 32*s + 8*lg + j;
        int c = 16*ct + lm;
        float v = (c < C_) ? cent[d*C_ + c] * nrmc[c] : 0.f;
        f[j] = (short)f2bf(v);
      }
      cnf[ct][s] = f;
    }
  }

  f32x4 acc[3][4];
  #pragma unroll
  for (int ct = 0; ct < 3; ++ct)
    #pragma unroll
    for (int nt = 0; nt < 4; ++nt) acc[ct][nt] = (f32x4){0.f,0.f,0.f,0.f};
  float sp[3][4];
  #pragma unroll
  for (int ct = 0; ct < 3; ++ct)
    #pragma unroll
    for (int r = 0; r < 4; ++r) sp[ct][r] = 0.f;

  // lane's global base: row = rowbase + lm, float col = 8*lg
  const float* px = x + ((size_t)(b*N_ + nb*512 + wid*128) + lm)*D_ + lg*8;

  float4 A0 = *(const float4*)(px +  0);
  float4 A1 = *(const float4*)(px +  4);
  float4 A2 = *(const float4*)(px + 32);
  float4 A3 = *(const float4*)(px + 36);

  for (int u = 0; u < 4; ++u) {
    #pragma unroll
    for (int g2 = 0; g2 < 2; ++g2) {
      const int g = u*2 + g2;
      float4 c0 = A0, c1 = A1, c2 = A2, c3 = A3;
      if (g < 7) {
        const float* pn = px + (size_t)(g+1)*16*D_;
        A0 = *(const float4*)(pn +  0);
        A1 = *(const float4*)(pn +  4);
        A2 = *(const float4*)(pn + 32);
        A3 = *(const float4*)(pn + 36);
      }
      // row sum-of-squares (16 elems per lane, + reduce over 4 lanes of row)
      float ss = 0.f;
      ss = fmaf(c0.x,c0.x,ss); ss = fmaf(c0.y,c0.y,ss); ss = fmaf(c0.z,c0.z,ss); ss = fmaf(c0.w,c0.w,ss);
      ss = fmaf(c1.x,c1.x,ss); ss = fmaf(c1.y,c1.y,ss); ss = fmaf(c1.z,c1.z,ss); ss = fmaf(c1.w,c1.w,ss);
      ss = fmaf(c2.x,c2.x,ss); ss = fmaf(c2.y,c2.y,ss); ss = fmaf(c2.z,c2.z,ss); ss = fmaf(c2.w,c2.w,ss);
      ss = fmaf(c3.x,c3.x,ss); ss = fmaf(c3.y,c3.y,ss); ss = fmaf(c3.z,c3.z,ss); ss = fmaf(c3.w,c3.w,ss);
      ss += __shfl_xor(ss, 16);
      ss += __shfl_xor(ss, 32);
      float rn = 1.f / fmaxf(sqrtf(ss), 1e-12f);

      // bf16 hi/lo fragments: kstep0 = d[8lg..8lg+7], kstep1 = d[32+8lg..]
      bf16x8 bh0, bl0, bh1, bl1;
      CVT1(c0.x,bh0,bl0,0) CVT1(c0.y,bh0,bl0,1) CVT1(c0.z,bh0,bl0,2) CVT1(c0.w,bh0,bl0,3)
      CVT1(c1.x,bh0,bl0,4) CVT1(c1.y,bh0,bl0,5) CVT1(c1.z,bh0,bl0,6) CVT1(c1.w,bh0,bl0,7)
      CVT1(c2.x,bh1,bl1,0) CVT1(c2.y,bh1,bl1,1) CVT1(c2.z,bh1,bl1,2) CVT1(c2.w,bh1,bl1,3)
      CVT1(c3.x,bh1,bl1,4) CVT1(c3.y,bh1,bl1,5) CVT1(c3.z,bh1,bl1,6) CVT1(c3.w,bh1,bl1,7)

      // cos GEMM: D[m=c][n=row] = cn . x   (raw x; scale by rn afterwards)
      f32x4 q[3];
      #pragma unroll
      for (int ct = 0; ct < 3; ++ct) q[ct] = (f32x4){0.f,0.f,0.f,0.f};
      q[0] = MFMA(cnf[0][0], bh0, q[0]); q[0] = MFMA(cnf[0][1], bh1, q[0]);
      q[0] = MFMA(cnf[0][0], bl0, q[0]); q[0] = MFMA(cnf[0][1], bl1, q[0]);
      q[1] = MFMA(cnf[1][0], bh0, q[1]); q[1] = MFMA(cnf[1][1], bh1, q[1]);
      q[1] = MFMA(cnf[1][0], bl0, q[1]); q[1] = MFMA(cnf[1][1], bl1, q[1]);
      q[2] = MFMA(cnf[2][0], bh0, q[2]); q[2] = MFMA(cnf[2][1], bh1, q[2]);
      q[2] = MFMA(cnf[2][0], bl0, q[2]); q[2] = MFMA(cnf[2][1], bl1, q[2]);

      // softmax over c (lane holds c = 16*ct + 4*lg + r for its own row = lm)
      float e[3][4]; float psum = 0.f;
      #pragma unroll
      for (int ct = 0; ct < 3; ++ct) {
        #pragma unroll
        for (int r = 0; r < 4; ++r) {
          int c = 16*ct + 4*lg + r;
          float ev = (c < C_) ? __expf(ALPHA_ * rn * q[ct][r]) : 0.f;
          e[ct][r] = ev; psum += ev;
        }
      }
      psum += __shfl_xor(psum, 16);
      psum += __shfl_xor(psum, 32);
      float inva = 1.f / psum;
      float arn  = inva * rn;

      const int rowin = g2*16 + lm;
      #pragma unroll
      for (int ct = 0; ct < 3; ++ct) {
        #pragma unroll
        for (int r = 0; r < 4; ++r) {
          sp[ct][r] = fmaf(q[ct][r]*rn, e[ct][r]*inva, sp[ct][r]);
          sh.m.asg[wid][(16*ct + 4*lg + r)*36 + rowin] = f2bf(e[ct][r] * arn);
        }
      }
      #pragma unroll
      for (int j = 0; j < 8; ++j) {
        sh.m.xt[wid][(     8*lg + j)*36 + rowin] = (unsigned short)bh0[j];
        sh.m.xt[wid][(32 + 8*lg + j)*36 + rowin] = (unsigned short)bh1[j];
      }
    }

    // ws GEMM over this 32-row unit: D[m=c][n=d] += asg(c,row) * x(row,d)
    bf16x8 af0 = ld_frag(&sh.m.asg[wid][( 0 + lm)*36 + 8*lg]);
    bf16x8 af1 = ld_frag(&sh.m.asg[wid][(16 + lm)*36 + 8*lg]);
    bf16x8 af2 = ld_frag(&sh.m.asg[wid][(32 + lm)*36 + 8*lg]);
    #pragma unroll
    for (int nt = 0; nt < 4; ++nt) {
      bf16x8 xf = ld_frag(&sh.m.xt[wid][(16*nt + lm)*36 + 8*lg]);
      acc[0][nt] = MFMA(af0, xf, acc[0][nt]);
      acc[1][nt] = MFMA(af1, xf, acc[1][nt]);
      acc[2][nt] = MFMA(af2, xf, acc[2][nt]);
    }
  }

  // ---- epilogue: self_product ----
  #pragma unroll
  for (int ct = 0; ct < 3; ++ct) {
    #pragma unroll
    for (int r = 0; r < 4; ++r) {
      float v = sp[ct][r];
      v += __shfl_xor(v, 1); v += __shfl_xor(v, 2);
      v += __shfl_xor(v, 4); v += __shfl_xor(v, 8);
      if (lm == 0) {
        int c = 16*ct + 4*lg + r;
        if (c < C_) atomicAdd(&spA[b*CP_ + c], v);
      }
    }
  }

  // ---- epilogue: combine 4 waves' ws in LDS, then global atomics ----
  __syncthreads();
  for (int w = 0; w < 4; ++w) {
    if (wid == w) {
      #pragma unroll
      for (int ct = 0; ct < 3; ++ct)
        #pragma unroll
        for (int nt = 0; nt < 4; ++nt)
          #pragma unroll
          for (int r = 0; r < 4; ++r) {
            int c = 16*ct + 4*lg + r;
            int d = 16*nt + lm;
            float* p = &sh.red[c*65 + d];
            if (w == 0) *p = acc[ct][nt][r]; else *p += acc[ct][nt][r];
          }
    }
    __syncthreads();
  }
  for (int i = t; i < C_*D_; i += 256) {
    int c = i >> 6, d = i & 63;
    atomicAdd(&wsA[(size_t)b*(C_*D_) + i], sh.red[c*65 + d]);
  }
}

// ---------------------------------------------------------------------------
// Finalize: one block per batch. wsA layout is [b][c][d] (vlad orientation).
// ---------------------------------------------------------------------------
__global__ __launch_bounds__(256) void k_final(
    const float* __restrict__ cent, const float* __restrict__ wsA,
    const float* __restrict__ spA, float* __restrict__ out)
{
  const int b = blockIdx.x;
  const int t = threadIdx.x;
  __shared__ float nrmc[C_];
  __shared__ float vl[C_][65];
  __shared__ float rc[C_];
  __shared__ float red[4];

  if (t < C_) {
    float ss = 0.f;
    for (int d = 0; d < D_; ++d) { float v = cent[d*C_ + t]; ss = fmaf(v, v, ss); }
    nrmc[t] = 1.f / fmaxf(sqrtf(ss), 1e-12f);
  }
  __syncthreads();
  for (int idx = t; idx < C_*D_; idx += 256) {
    int c = idx >> 6, d = idx & 63;
    float cn = cent[d*C_ + c] * nrmc[c];
    vl[c][d] = wsA[(size_t)b*(C_*D_) + idx] - cn * spA[b*CP_ + c];
  }
  __syncthreads();
  if (t < C_) {
    float ss = 0.f;
    for (int d = 0; d < D_; ++d) { float v = vl[t][d]; ss = fmaf(v, v, ss); }
    rc[t] = 1.f / fmaxf(sqrtf(ss), 1e-12f);
  }
  __syncthreads();
  float p = 0.f;
  for (int idx = t; idx < C_*D_; idx += 256) {
    int c = idx >> 6, d = idx & 63;
    float v = vl[c][d] * rc[c];
    p = fmaf(v, v, p);
  }
  for (int off = 32; off; off >>= 1) p += __shfl_down(p, off);
  if ((t & 63) == 0) red[t >> 6] = p;
  __syncthreads();
  float S = red[0] + red[1] + red[2] + red[3];
  float rg = 1.f / fmaxf(sqrtf(S), 1e-12f);
  for (int idx = t; idx < FG_*D_; idx += 256) {
    int c = idx >> 6, d = idx & 63;
    out[(size_t)b*(FG_*D_) + idx] = vl[c][d] * rc[c] * rg;
  }
}

extern "C" void kernel_launch(void* const* d_in, const int* in_sizes, int n_in,
                              void* d_out, int out_size, void* d_ws, size_t ws_size,
                              hipStream_t stream) {
  const float* x    = (const float*)d_in[0];
  const float* cent = (const float*)d_in[1];
  float* out = (float*)d_out;

  float* wsA = (float*)d_ws;                    // 32 * 36 * 64 floats ([b][c][d])
  float* spA = wsA + (size_t)B_*C_*D_;          // 32 * 48 floats

  hipMemsetAsync(d_ws, 0, ((size_t)B_*C_*D_ + (size_t)B_*CP_) * sizeof(float), stream);

  k_accum<<<1024, 256, 0, stream>>>(x, cent, wsA, spA);
  k_final<<<B_, 256, 0, stream>>>(cent, wsA, spA, out);
}